// Round 4
// baseline (451.528 us; speedup 1.0000x reference)
//
#include <hip/hip_runtime.h>

#define N_NODES 20000
#define C 64
#define E_EDGES 320000
#define S_SPEC 64
#define R_DIM 8
#define HR 64
#define HEADS 2
#define TE 128
#define NT (E_EDGES/TE)          // 2500 blocks
#define HPAD 68                  // padded bf16 row stride (k-dim)
#define INV_AVG (1.0f/16.0f)

// out layout: node_out [0,40000) ; f_s [40000, 1320000) ; f_v [1320000, 5160000)
#define FS_OFF 40000
#define FV_OFF 1320000

typedef short bf16x4 __attribute__((ext_vector_type(4)));
typedef float f32x4  __attribute__((ext_vector_type(4)));

__device__ __forceinline__ unsigned short f2bf(float f){
  unsigned u = __float_as_uint(f);
  u += 0x7fffu + ((u >> 16) & 1u);
  return (unsigned short)(u >> 16);
}
__device__ __forceinline__ float bf2f(unsigned short b){
  return __uint_as_float(((unsigned)b) << 16);
}
__device__ __forceinline__ float phi_f(float x){
  float n = x * 0.5f;
  float s = (n > 0.0f) ? expf(-1.0f/n) : 0.0f;
  return 1.0f / (1.0f + n * s);
}

// ---------------- prep: Wr2T[n][k] = bf16(Wr2[k][n] / AVG)  (320x64) ------------------
__global__ __launch_bounds__(256) void wr2t_kernel(const float* __restrict__ Wr2,
                                                   unsigned short* __restrict__ wr2t){
  int idx = blockIdx.x*256 + threadIdx.x;      // n*64 + k
  int n = idx >> 6, k = idx & 63;
  wr2t[idx] = f2bf(Wr2[k*320 + n] * INV_AVG);
}

// ---------------- K1: up-projection, writes packed bf16 suv[n][c] = {s,v0,v1,v2} ------
__global__ __launch_bounds__(256) void node_up_kernel(
    const float* __restrict__ fs, const float* __restrict__ fv,
    const float* __restrict__ Wus, const float* __restrict__ Wuv,
    ushort4* __restrict__ suv){
  const int ni = threadIdx.x >> 6;
  const int d  = threadIdx.x & 63;
  const int n  = blockIdx.x*4 + ni;
  __shared__ float s_l[4][C];
  __shared__ float v_l[4][3][C];
  s_l[ni][d] = fs[n*C + d];
  #pragma unroll
  for (int x = 0; x < 3; ++x) v_l[ni][x][d] = fv[(n*C + d)*3 + x];
  __syncthreads();
  float as = 0.f, a0 = 0.f, a1 = 0.f, a2 = 0.f;
  #pragma unroll 4
  for (int c = 0; c < C; ++c){
    float wsv = Wus[c*C + d];
    float wvv = Wuv[c*C + d];
    as += s_l[ni][c] * wsv;
    a0 += v_l[ni][0][c] * wvv;
    a1 += v_l[ni][1][c] * wvv;
    a2 += v_l[ni][2][c] * wvv;
  }
  ushort4 o;
  o.x = f2bf(as); o.y = f2bf(a0); o.z = f2bf(a1); o.w = f2bf(a2);
  suv[(size_t)n*C + d] = o;
}

// ---------------- sort pass A: histogram of receivers ---------------------------------
__global__ __launch_bounds__(256) void hist_kernel(const int* __restrict__ rcv, int* __restrict__ count){
  int e = blockIdx.x*256 + threadIdx.x;
  atomicAdd(&count[rcv[e]], 1);
}

// ---------------- sort pass B: exclusive scan over 20000 counts (1 block) -------------
__global__ __launch_bounds__(1024) void scan_kernel(const int* __restrict__ count, int* __restrict__ cursor){
  __shared__ int sums[1024];
  const int t = threadIdx.x;
  const int base = t*20;
  int s = 0;
  #pragma unroll 4
  for (int i = 0; i < 20; ++i){ int idx = base+i; if (idx < N_NODES) s += count[idx]; }
  sums[t] = s;
  __syncthreads();
  for (int off = 1; off < 1024; off <<= 1){
    int v = (t >= off) ? sums[t-off] : 0;
    __syncthreads();
    sums[t] += v;
    __syncthreads();
  }
  int run = (t > 0) ? sums[t-1] : 0;
  for (int i = 0; i < 20; ++i){
    int idx = base+i;
    if (idx < N_NODES){ cursor[idx] = run; run += count[idx]; }
  }
}

// ---------------- sort pass C: permutation only (4B scattered writes) -----------------
__global__ __launch_bounds__(256) void perm_kernel(
    const int* __restrict__ rcv, int* __restrict__ cursor, int* __restrict__ perm){
  int e = blockIdx.x*256 + threadIdx.x;
  int pos = atomicAdd(&cursor[rcv[e]], 1);
  perm[pos] = e;
}

// ---------------- K2: MFMA radial GEMM + prefetched bf16 gather + run-length scatter --
__global__ __launch_bounds__(512, 4) void edge_kernel(
    const float* __restrict__ ev, const float* __restrict__ re,
    const int* __restrict__ snd, const int* __restrict__ rcv,
    const int* __restrict__ perm,
    const float* __restrict__ Wr1, const unsigned short* __restrict__ wr2t,
    const ushort4* __restrict__ suv,
    float* __restrict__ a_s, float* __restrict__ a_v)
{
  __shared__ __align__(16) float Wr1_l[R_DIM*HR];            // 2 KB
  __shared__ __align__(16) unsigned short Wr2T_l[320*HPAD];  // 43.5 KB bf16 [n][k] padded
  __shared__ __align__(16) unsigned short h_l[TE*HPAD];      // 17.4 KB bf16 [e][k] padded
  __shared__ float u_l[TE][4];
  __shared__ int snd_l[TE];
  __shared__ int rcv_l[TE];
  __shared__ int pe_l[TE];

  const int t = threadIdx.x;
  const int lane = t & 63;
  const int w = t >> 6;                 // wave 0..7 = 16-edge row-block
  // bijective XCD swizzle over 2500 blocks (2500 = 8*312 + 4)
  int b = blockIdx.x;
  int xcd = b & 7, idx = b >> 3;
  const int q = NT >> 3, r = NT & 7;
  int tile = (xcd < r ? xcd*(q+1) : r*(q+1) + (xcd-r)*q) + idx;
  const int e0 = tile * TE;

  // ---- stage Wr1, Wr2T (padded), edge meta via perm ----
  Wr1_l[t] = Wr1[t];
  #pragma unroll
  for (int j = 0; j < 10; ++j){
    int i4 = t + 512*j;                 // ushort4 index, 5120 total
    ushort4 v4 = ((const ushort4*)wr2t)[i4];
    int el = i4*4; int n = el >> 6, k = el & 63;
    *(ushort4*)&Wr2T_l[n*HPAD + k] = v4;
  }
  if (t < TE){
    int e = perm[e0 + t];
    pe_l[t] = e;
    float x = ev[e*3+0], y = ev[e*3+1], z = ev[e*3+2];
    float nr = sqrtf(x*x + y*y + z*z);
    float inv = 1.0f / fmaxf(nr, 1e-9f);
    u_l[t][0] = x*inv; u_l[t][1] = y*inv; u_l[t][2] = z*inv;
    snd_l[t] = snd[e];
    rcv_l[t] = rcv[e];
  }
  __syncthreads();

  // ---- prefetch sender-feature gather (consumed after MFMA; hides under h+MFMA) ----
  const int cl = lane & 15;
  const int ebase = w*16 + (lane >> 4)*4;     // this lane's 4 edges
  ushort4 gv[4][4];
  #pragma unroll
  for (int i = 0; i < 4; ++i){
    const ushort4* sp_ = &suv[(size_t)snd_l[ebase + i]*C];
    #pragma unroll
    for (int k2 = 0; k2 < 4; ++k2) gv[i][k2] = sp_[k2*16 + cl];
  }

  // ---- h = silu(re @ Wr1) in bf16: thread (e = t&127, qh = t>>7) does k = qh*16..+16
  {
    int e = t & 127, qh = t >> 7;
    const float4* rp = (const float4*)&re[(size_t)pe_l[e]*R_DIM];
    float4 ra = rp[0], rb = rp[1];
    unsigned short hh[16];
    #pragma unroll
    for (int kk = 0; kk < 16; ++kk){
      int k = qh*16 + kk;
      float acc = ra.x*Wr1_l[0*HR+k] + ra.y*Wr1_l[1*HR+k] + ra.z*Wr1_l[2*HR+k] + ra.w*Wr1_l[3*HR+k]
                + rb.x*Wr1_l[4*HR+k] + rb.y*Wr1_l[5*HR+k] + rb.z*Wr1_l[6*HR+k] + rb.w*Wr1_l[7*HR+k];
      hh[kk] = f2bf(acc / (1.0f + expf(-acc)));
    }
    #pragma unroll
    for (int j4 = 0; j4 < 4; ++j4)
      *(ushort4*)&h_l[e*HPAD + qh*16 + j4*4] = *(ushort4*)&hh[j4*4];
  }
  __syncthreads();

  // ---- MFMA: W5[128][320] = h @ Wr2T^T, wave w owns rows w*16..+16, all 20 col-frags
  f32x4 acc[20];
  #pragma unroll
  for (int cf = 0; cf < 20; ++cf) acc[cf] = (f32x4){0.f,0.f,0.f,0.f};
  {
    const int arow = (w*16 + (lane & 15))*HPAD;
    const int koff = 4*(lane >> 4);
    #pragma unroll
    for (int kt = 0; kt < 4; ++kt){
      bf16x4 af = *(const bf16x4*)&h_l[arow + kt*16 + koff];
      #pragma unroll
      for (int cf = 0; cf < 20; ++cf){
        bf16x4 bf = *(const bf16x4*)&Wr2T_l[(cf*16 + (lane & 15))*HPAD + kt*16 + koff];
        acc[cf] = __builtin_amdgcn_mfma_f32_16x16x16bf16_1k(af, bf, acc[cf], 0, 0, 0);
      }
    }
  }

  // ---- messages, register-resident; bf16 sender feats from prefetched gv ----
  {
    float ms[4], mv0[4], mv1[4], mv2[4];
    #pragma unroll
    for (int k2 = 0; k2 < 4; ++k2){ ms[k2]=0.f; mv0[k2]=0.f; mv1[k2]=0.f; mv2[k2]=0.f; }
    int cur = rcv_l[ebase];
    #pragma unroll
    for (int i = 0; i < 4; ++i){
      int el = ebase + i;
      int rc = rcv_l[el];
      if (rc != cur){
        #pragma unroll
        for (int k2 = 0; k2 < 4; ++k2){
          int c = k2*16 + cl;
          unsafeAtomicAdd(&a_s[cur*C + c],       ms[k2]);
          unsafeAtomicAdd(&a_v[(cur*3+0)*C + c], mv0[k2]);
          unsafeAtomicAdd(&a_v[(cur*3+1)*C + c], mv1[k2]);
          unsafeAtomicAdd(&a_v[(cur*3+2)*C + c], mv2[k2]);
          ms[k2]=0.f; mv0[k2]=0.f; mv1[k2]=0.f; mv2[k2]=0.f;
        }
        cur = rc;
      }
      float u0 = u_l[el][0], u1 = u_l[el][1], u2 = u_l[el][2];
      #pragma unroll
      for (int k2 = 0; k2 < 4; ++k2){
        float se  = bf2f(gv[i][k2].x);
        float ve0 = bf2f(gv[i][k2].y);
        float ve1 = bf2f(gv[i][k2].z);
        float ve2 = bf2f(gv[i][k2].w);
        float w0 = acc[0*4+k2][i];
        float w1 = acc[1*4+k2][i];
        float w2 = acc[2*4+k2][i];
        float w3 = acc[3*4+k2][i];
        float w4 = acc[4*4+k2][i];
        float dt  = ve0*u0 + ve1*u1 + ve2*u2;
        float cr0 = ve1*u2 - ve2*u1;
        float cr1 = ve2*u0 - ve0*u2;
        float cr2 = ve0*u1 - ve1*u0;
        ms[k2]  += w0*se + w3*dt;
        mv0[k2] += w1*ve0 + w2*u0 + w4*cr0;
        mv1[k2] += w1*ve1 + w2*u1 + w4*cr1;
        mv2[k2] += w1*ve2 + w2*u2 + w4*cr2;
      }
    }
    #pragma unroll
    for (int k2 = 0; k2 < 4; ++k2){
      int c = k2*16 + cl;
      unsafeAtomicAdd(&a_s[cur*C + c],       ms[k2]);
      unsafeAtomicAdd(&a_v[(cur*3+0)*C + c], mv0[k2]);
      unsafeAtomicAdd(&a_v[(cur*3+1)*C + c], mv1[k2]);
      unsafeAtomicAdd(&a_v[(cur*3+2)*C + c], mv2[k2]);
    }
  }
}

// ---------------- K3: down-matvec, product basis, soft-norm, residual, readout (4/blk)
__global__ __launch_bounds__(256) void node_post_kernel(
    const float* __restrict__ a_s, const float* __restrict__ a_v,
    const float* __restrict__ fs_in, const float* __restrict__ fv_in,
    const int* __restrict__ species,
    const float* __restrict__ W_rs, const float* __restrict__ W_rv,
    const float* __restrict__ W_ds, const float* __restrict__ W_dv,
    const float* __restrict__ w1s, const float* __restrict__ w1v,
    const float* __restrict__ w2ss, const float* __restrict__ w2vv, const float* __restrict__ w2sv,
    const float* __restrict__ W_ps, const float* __restrict__ W_pv,
    const float* __restrict__ w_read, float* __restrict__ out)
{
  const int ni = threadIdx.x >> 6;
  const int d  = threadIdx.x & 63;
  const int n  = blockIdx.x*4 + ni;
  const int sp = species[n];
  __shared__ float as_l[4][C];
  __shared__ float av_l[4][3][C];
  __shared__ float si_l[4][C];
  __shared__ float vi_l[4][3][C];
  as_l[ni][d] = a_s[n*C + d];
  #pragma unroll
  for (int x=0;x<3;x++) av_l[ni][x][d] = a_v[(n*3+x)*C + d];
  si_l[ni][d] = fs_in[n*C + d];
  #pragma unroll
  for (int x=0;x<3;x++) vi_l[ni][x][d] = fv_in[(n*C + d)*3 + x];
  __syncthreads();
  const float* Wrs_p = W_rs + sp*C*C;
  const float* Wrv_p = W_rv + sp*C*C;
  float bs=0, bv0=0, bv1=0, bv2=0, rs=0, rv0=0, rv1=0, rv2=0;
  for (int c=0;c<C;++c){
    float wds = W_ds[c*C+d], wdv = W_dv[c*C+d];
    float wrs = Wrs_p[c*C+d], wrv = Wrv_p[c*C+d];
    bs  += as_l[ni][c]*wds;
    bv0 += av_l[ni][0][c]*wdv; bv1 += av_l[ni][1][c]*wdv; bv2 += av_l[ni][2][c]*wdv;
    rs  += si_l[ni][c]*wrs;
    rv0 += vi_l[ni][0][c]*wrv; rv1 += vi_l[ni][1][c]*wrv; rv2 += vi_l[ni][2][c]*wrv;
  }
  float vv = bv0*bv0 + bv1*bv1 + bv2*bv2;
  float ps  = w1s[sp*C+d]*bs + w2ss[sp*C+d]*bs*bs + w2vv[sp*C+d]*vv;
  float c1v = w1v[sp*C+d], c2sv = w2sv[sp*C+d];
  float pv0 = c1v*bv0 + c2sv*bs*bv0;
  float pv1 = c1v*bv1 + c2sv*bs*bv1;
  float pv2 = c1v*bv2 + c2sv*bs*bv2;
  __syncthreads();
  as_l[ni][d] = ps; av_l[ni][0][d]=pv0; av_l[ni][1][d]=pv1; av_l[ni][2][d]=pv2;
  __syncthreads();
  float qs=0, qv0=0, qv1=0, qv2=0;
  for (int c=0;c<C;++c){
    float wps = W_ps[c*C+d], wpv = W_pv[c*C+d];
    qs  += as_l[ni][c]*wps;
    qv0 += av_l[ni][0][c]*wpv; qv1 += av_l[ni][1][c]*wpv; qv2 += av_l[ni][2][c]*wpv;
  }
  float fsv = qs * phi_f(fabsf(qs)) + rs;
  float nv = sqrtf(qv0*qv0 + qv1*qv1 + qv2*qv2);
  float ph = phi_f(nv);
  float fv0 = qv0*ph + rv0;
  float fv1 = qv1*ph + rv1;
  float fv2 = qv2*ph + rv2;
  out[FS_OFF + n*C + d] = fsv;
  float* fvo = &out[FV_OFF + (size_t)(n*C + d)*3];
  fvo[0]=fv0; fvo[1]=fv1; fvo[2]=fv2;
  #pragma unroll
  for (int h=0; h<HEADS; ++h){
    float r = fsv * w_read[h*C + d];
    #pragma unroll
    for (int off=32; off>0; off>>=1) r += __shfl_down(r, off);
    if (d == 0) out[n*HEADS + h] = r;
  }
}

extern "C" void kernel_launch(void* const* d_in, const int* in_sizes, int n_in,
                              void* d_out, int out_size, void* d_ws, size_t ws_size,
                              hipStream_t stream)
{
  const float* ev   = (const float*)d_in[0];
  const float* nfs  = (const float*)d_in[1];
  const float* nfv  = (const float*)d_in[2];
  const float* re   = (const float*)d_in[3];
  const int*   spec = (const int*)d_in[4];
  const int*   snd  = (const int*)d_in[5];
  const int*   rcv  = (const int*)d_in[6];
  const float* W_rs = (const float*)d_in[7];
  const float* W_rv = (const float*)d_in[8];
  const float* Wus  = (const float*)d_in[9];
  const float* Wuv  = (const float*)d_in[10];
  const float* Wr1  = (const float*)d_in[11];
  const float* Wr2  = (const float*)d_in[12];
  const float* Wds  = (const float*)d_in[13];
  const float* Wdv  = (const float*)d_in[14];
  const float* w1s  = (const float*)d_in[15];
  const float* w1v  = (const float*)d_in[16];
  const float* w2ss = (const float*)d_in[17];
  const float* w2vv = (const float*)d_in[18];
  const float* w2sv = (const float*)d_in[19];
  const float* Wps  = (const float*)d_in[20];
  const float* Wpv  = (const float*)d_in[21];
  const float* wrd  = (const float*)d_in[22];

  float* out = (float*)d_out;
  float* ws  = (float*)d_ws;
  // ws layout (f32 units)
  ushort4* suv  = (ushort4*)ws;            // 10.24 MB  (= 2,560,000 f32)
  float*   a_s  = ws + 2560000;            // 1,280,000
  float*   a_v  = ws + 3840000;            // 3,840,000
  int*    count = (int*)(ws + 7680000);    // 20,000
  int*    cursr = (int*)(ws + 7700000);    // 20,000
  int*    perm  = (int*)(ws + 7720000);    // 320,000
  unsigned short* wr2t = (unsigned short*)(ws + 8040000);  // 20,480 bf16

  hipMemsetAsync(a_s, 0, (size_t)5120000*sizeof(float), stream);   // a_s + a_v
  hipMemsetAsync(count, 0, (size_t)N_NODES*sizeof(int), stream);

  wr2t_kernel<<<(320*64)/256, 256, 0, stream>>>(Wr2, wr2t);
  node_up_kernel<<<N_NODES/4, 256, 0, stream>>>(nfs, nfv, Wus, Wuv, suv);
  hist_kernel<<<E_EDGES/256, 256, 0, stream>>>(rcv, count);
  scan_kernel<<<1, 1024, 0, stream>>>(count, cursr);
  perm_kernel<<<E_EDGES/256, 256, 0, stream>>>(rcv, cursr, perm);
  edge_kernel<<<NT, 512, 0, stream>>>(ev, re, snd, rcv, perm, Wr1, wr2t,
                                      suv, a_s, a_v);
  node_post_kernel<<<N_NODES/4, 256, 0, stream>>>(a_s, a_v, nfs, nfv, spec,
      W_rs, W_rv, Wds, Wdv, w1s, w1v, w2ss, w2vv, w2sv, Wps, Wpv, wrd, out);
}

// Round 5
// 433.863 us; speedup vs baseline: 1.0407x; 1.0407x over previous
//
#include <hip/hip_runtime.h>

#define N_NODES 20000
#define C 64
#define E_EDGES 320000
#define S_SPEC 64
#define R_DIM 8
#define HR 64
#define HEADS 2
#define TE 128
#define NT (E_EDGES/TE)          // 2500 blocks
#define HPAD 68                  // padded bf16 row stride (k-dim)
#define INV_AVG (1.0f/16.0f)

// out layout: node_out [0,40000) ; f_s [40000, 1320000) ; f_v [1320000, 5160000)
#define FS_OFF 40000
#define FV_OFF 1320000

typedef short bf16x4 __attribute__((ext_vector_type(4)));
typedef float f32x4  __attribute__((ext_vector_type(4)));

__device__ __forceinline__ unsigned short f2bf(float f){
  unsigned u = __float_as_uint(f);
  u += 0x7fffu + ((u >> 16) & 1u);
  return (unsigned short)(u >> 16);
}
__device__ __forceinline__ float bf2f(unsigned short b){
  return __uint_as_float(((unsigned)b) << 16);
}
__device__ __forceinline__ float phi_f(float x){
  float n = x * 0.5f;
  float s = (n > 0.0f) ? expf(-1.0f/n) : 0.0f;
  return 1.0f / (1.0f + n * s);
}

// ---------------- prep: Wr2T[n][k] = bf16(Wr2[k][n] / AVG)  (320x64) ------------------
__global__ __launch_bounds__(256) void wr2t_kernel(const float* __restrict__ Wr2,
                                                   unsigned short* __restrict__ wr2t){
  int idx = blockIdx.x*256 + threadIdx.x;      // n*64 + k
  int n = idx >> 6, k = idx & 63;
  wr2t[idx] = f2bf(Wr2[k*320 + n] * INV_AVG);
}

// ---------------- K1: up-projection, writes packed bf16 suv[n][c] = {s,v0,v1,v2} ------
__global__ __launch_bounds__(256) void node_up_kernel(
    const float* __restrict__ fs, const float* __restrict__ fv,
    const float* __restrict__ Wus, const float* __restrict__ Wuv,
    ushort4* __restrict__ suv){
  const int ni = threadIdx.x >> 6;
  const int d  = threadIdx.x & 63;
  const int n  = blockIdx.x*4 + ni;
  __shared__ float s_l[4][C];
  __shared__ float v_l[4][3][C];
  s_l[ni][d] = fs[n*C + d];
  #pragma unroll
  for (int x = 0; x < 3; ++x) v_l[ni][x][d] = fv[(n*C + d)*3 + x];
  __syncthreads();
  float as = 0.f, a0 = 0.f, a1 = 0.f, a2 = 0.f;
  #pragma unroll 4
  for (int c = 0; c < C; ++c){
    float wsv = Wus[c*C + d];
    float wvv = Wuv[c*C + d];
    as += s_l[ni][c] * wsv;
    a0 += v_l[ni][0][c] * wvv;
    a1 += v_l[ni][1][c] * wvv;
    a2 += v_l[ni][2][c] * wvv;
  }
  ushort4 o;
  o.x = f2bf(as); o.y = f2bf(a0); o.z = f2bf(a1); o.w = f2bf(a2);
  suv[(size_t)n*C + d] = o;
}

// ---------------- sort pass A: histogram of receivers ---------------------------------
__global__ __launch_bounds__(256) void hist_kernel(const int* __restrict__ rcv, int* __restrict__ count){
  int e = blockIdx.x*256 + threadIdx.x;
  atomicAdd(&count[rcv[e]], 1);
}

// ---------------- sort pass B: exclusive scan over 20000 counts (1 block) -------------
__global__ __launch_bounds__(1024) void scan_kernel(const int* __restrict__ count, int* __restrict__ cursor){
  __shared__ int sums[1024];
  const int t = threadIdx.x;
  const int base = t*20;
  int s = 0;
  #pragma unroll 4
  for (int i = 0; i < 20; ++i){ int idx = base+i; if (idx < N_NODES) s += count[idx]; }
  sums[t] = s;
  __syncthreads();
  for (int off = 1; off < 1024; off <<= 1){
    int v = (t >= off) ? sums[t-off] : 0;
    __syncthreads();
    sums[t] += v;
    __syncthreads();
  }
  int run = (t > 0) ? sums[t-1] : 0;
  for (int i = 0; i < 20; ++i){
    int idx = base+i;
    if (idx < N_NODES){ cursor[idx] = run; run += count[idx]; }
  }
}

// ---------------- sort pass C: scatter into sorted arrays, u pre-normalized ----------
__global__ __launch_bounds__(256) void scatter_kernel(
    const int* __restrict__ snd, const int* __restrict__ rcv,
    const float* __restrict__ ev, const float* __restrict__ re,
    int* __restrict__ cursor,
    int* __restrict__ snd_s, int* __restrict__ rcv_s,
    float4* __restrict__ u_s, float* __restrict__ re_s){
  int e = blockIdx.x*256 + threadIdx.x;
  int r = rcv[e];
  int pos = atomicAdd(&cursor[r], 1);
  snd_s[pos] = snd[e];
  rcv_s[pos] = r;
  float x = ev[e*3+0], y = ev[e*3+1], z = ev[e*3+2];
  float nr = sqrtf(x*x + y*y + z*z);
  float inv = 1.0f / fmaxf(nr, 1e-9f);
  float4 u4; u4.x = x*inv; u4.y = y*inv; u4.z = z*inv; u4.w = 0.f;
  u_s[pos] = u4;
  const float4* rp = (const float4*)&re[(size_t)e*R_DIM];
  float4 ra = rp[0], rb = rp[1];
  float4* op = (float4*)&re_s[(size_t)pos*R_DIM];
  op[0] = ra; op[1] = rb;
}

// ---------------- K2: MFMA radial GEMM + prefetched bf16 gather + run-length scatter --
__global__ __launch_bounds__(512, 4) void edge_kernel(
    const float4* __restrict__ u_s, const float* __restrict__ re_s,
    const int* __restrict__ snd_s, const int* __restrict__ rcv_s,
    const float* __restrict__ Wr1, const unsigned short* __restrict__ wr2t,
    const ushort4* __restrict__ suv,
    float* __restrict__ a_s, float* __restrict__ a_v)
{
  __shared__ __align__(16) float Wr1_l[R_DIM*HR];            // 2 KB
  __shared__ __align__(16) unsigned short Wr2T_l[320*HPAD];  // 43.5 KB bf16 [n][k] padded
  __shared__ __align__(16) unsigned short h_l[TE*HPAD];      // 17.4 KB bf16 [e][k] padded
  __shared__ __align__(16) float4 u_l[TE];                   // 2 KB
  __shared__ int snd_l[TE];
  __shared__ int rcv_l[TE];

  const int t = threadIdx.x;
  const int lane = t & 63;
  const int w = t >> 6;                 // wave 0..7 = 16-edge row-block
  // bijective XCD swizzle over 2500 blocks (2500 = 8*312 + 4)
  int b = blockIdx.x;
  int xcd = b & 7, idx = b >> 3;
  const int q = NT >> 3, r = NT & 7;
  int tile = (xcd < r ? xcd*(q+1) : r*(q+1) + (xcd-r)*q) + idx;
  const int e0 = tile * TE;

  // ---- stage Wr1, Wr2T (padded), edge meta (all sequential) ----
  Wr1_l[t] = Wr1[t];
  #pragma unroll
  for (int j = 0; j < 10; ++j){
    int i4 = t + 512*j;                 // ushort4 index, 5120 total
    ushort4 v4 = ((const ushort4*)wr2t)[i4];
    int el = i4*4; int n = el >> 6, k = el & 63;
    *(ushort4*)&Wr2T_l[n*HPAD + k] = v4;
  }
  if (t < TE){
    int e = e0 + t;
    u_l[t] = u_s[e];
    snd_l[t] = snd_s[e];
    rcv_l[t] = rcv_s[e];
  }
  __syncthreads();

  // ---- prefetch sender-feature gather (consumed after MFMA; hides under h+MFMA) ----
  const int cl = lane & 15;
  const int ebase = w*16 + (lane >> 4)*4;     // this lane's 4 edges
  ushort4 gv[4][4];
  #pragma unroll
  for (int i = 0; i < 4; ++i){
    const ushort4* sp_ = &suv[(size_t)snd_l[ebase + i]*C];
    #pragma unroll
    for (int k2 = 0; k2 < 4; ++k2) gv[i][k2] = sp_[k2*16 + cl];
  }

  // ---- h = silu(re @ Wr1) in bf16: thread (e = t&127, qh = t>>7) does k = qh*16..+16
  {
    int e = t & 127, qh = t >> 7;
    const float4* rp = (const float4*)&re_s[(size_t)(e0 + e)*R_DIM];
    float4 ra = rp[0], rb = rp[1];
    unsigned short hh[16];
    #pragma unroll
    for (int kk = 0; kk < 16; ++kk){
      int k = qh*16 + kk;
      float acc = ra.x*Wr1_l[0*HR+k] + ra.y*Wr1_l[1*HR+k] + ra.z*Wr1_l[2*HR+k] + ra.w*Wr1_l[3*HR+k]
                + rb.x*Wr1_l[4*HR+k] + rb.y*Wr1_l[5*HR+k] + rb.z*Wr1_l[6*HR+k] + rb.w*Wr1_l[7*HR+k];
      hh[kk] = f2bf(acc / (1.0f + expf(-acc)));
    }
    #pragma unroll
    for (int j4 = 0; j4 < 4; ++j4)
      *(ushort4*)&h_l[e*HPAD + qh*16 + j4*4] = *(ushort4*)&hh[j4*4];
  }
  __syncthreads();

  // ---- MFMA: W5[128][320] = h @ Wr2T^T, wave w owns rows w*16..+16, all 20 col-frags
  f32x4 acc[20];
  #pragma unroll
  for (int cf = 0; cf < 20; ++cf) acc[cf] = (f32x4){0.f,0.f,0.f,0.f};
  {
    const int arow = (w*16 + (lane & 15))*HPAD;
    const int koff = 4*(lane >> 4);
    #pragma unroll
    for (int kt = 0; kt < 4; ++kt){
      bf16x4 af = *(const bf16x4*)&h_l[arow + kt*16 + koff];
      #pragma unroll
      for (int cf = 0; cf < 20; ++cf){
        bf16x4 bf = *(const bf16x4*)&Wr2T_l[(cf*16 + (lane & 15))*HPAD + kt*16 + koff];
        acc[cf] = __builtin_amdgcn_mfma_f32_16x16x16bf16_1k(af, bf, acc[cf], 0, 0, 0);
      }
    }
  }

  // ---- messages, register-resident; bf16 sender feats from prefetched gv ----
  {
    float ms[4], mv0[4], mv1[4], mv2[4];
    #pragma unroll
    for (int k2 = 0; k2 < 4; ++k2){ ms[k2]=0.f; mv0[k2]=0.f; mv1[k2]=0.f; mv2[k2]=0.f; }
    int cur = rcv_l[ebase];
    #pragma unroll
    for (int i = 0; i < 4; ++i){
      int el = ebase + i;
      int rc = rcv_l[el];
      if (rc != cur){
        #pragma unroll
        for (int k2 = 0; k2 < 4; ++k2){
          int c = k2*16 + cl;
          unsafeAtomicAdd(&a_s[cur*C + c],       ms[k2]);
          unsafeAtomicAdd(&a_v[(cur*3+0)*C + c], mv0[k2]);
          unsafeAtomicAdd(&a_v[(cur*3+1)*C + c], mv1[k2]);
          unsafeAtomicAdd(&a_v[(cur*3+2)*C + c], mv2[k2]);
          ms[k2]=0.f; mv0[k2]=0.f; mv1[k2]=0.f; mv2[k2]=0.f;
        }
        cur = rc;
      }
      float u0 = u_l[el].x, u1 = u_l[el].y, u2 = u_l[el].z;
      #pragma unroll
      for (int k2 = 0; k2 < 4; ++k2){
        float se  = bf2f(gv[i][k2].x);
        float ve0 = bf2f(gv[i][k2].y);
        float ve1 = bf2f(gv[i][k2].z);
        float ve2 = bf2f(gv[i][k2].w);
        float w0 = acc[0*4+k2][i];
        float w1 = acc[1*4+k2][i];
        float w2 = acc[2*4+k2][i];
        float w3 = acc[3*4+k2][i];
        float w4 = acc[4*4+k2][i];
        float dt  = ve0*u0 + ve1*u1 + ve2*u2;
        float cr0 = ve1*u2 - ve2*u1;
        float cr1 = ve2*u0 - ve0*u2;
        float cr2 = ve0*u1 - ve1*u0;
        ms[k2]  += w0*se + w3*dt;
        mv0[k2] += w1*ve0 + w2*u0 + w4*cr0;
        mv1[k2] += w1*ve1 + w2*u1 + w4*cr1;
        mv2[k2] += w1*ve2 + w2*u2 + w4*cr2;
      }
    }
    #pragma unroll
    for (int k2 = 0; k2 < 4; ++k2){
      int c = k2*16 + cl;
      unsafeAtomicAdd(&a_s[cur*C + c],       ms[k2]);
      unsafeAtomicAdd(&a_v[(cur*3+0)*C + c], mv0[k2]);
      unsafeAtomicAdd(&a_v[(cur*3+1)*C + c], mv1[k2]);
      unsafeAtomicAdd(&a_v[(cur*3+2)*C + c], mv2[k2]);
    }
  }
}

// ---------------- K3: down-matvec, product basis, soft-norm, residual, readout (4/blk)
__global__ __launch_bounds__(256) void node_post_kernel(
    const float* __restrict__ a_s, const float* __restrict__ a_v,
    const float* __restrict__ fs_in, const float* __restrict__ fv_in,
    const int* __restrict__ species,
    const float* __restrict__ W_rs, const float* __restrict__ W_rv,
    const float* __restrict__ W_ds, const float* __restrict__ W_dv,
    const float* __restrict__ w1s, const float* __restrict__ w1v,
    const float* __restrict__ w2ss, const float* __restrict__ w2vv, const float* __restrict__ w2sv,
    const float* __restrict__ W_ps, const float* __restrict__ W_pv,
    const float* __restrict__ w_read, float* __restrict__ out)
{
  const int ni = threadIdx.x >> 6;
  const int d  = threadIdx.x & 63;
  const int n  = blockIdx.x*4 + ni;
  const int sp = species[n];
  __shared__ float as_l[4][C];
  __shared__ float av_l[4][3][C];
  __shared__ float si_l[4][C];
  __shared__ float vi_l[4][3][C];
  as_l[ni][d] = a_s[n*C + d];
  #pragma unroll
  for (int x=0;x<3;x++) av_l[ni][x][d] = a_v[(n*3+x)*C + d];
  si_l[ni][d] = fs_in[n*C + d];
  #pragma unroll
  for (int x=0;x<3;x++) vi_l[ni][x][d] = fv_in[(n*C + d)*3 + x];
  __syncthreads();
  const float* Wrs_p = W_rs + sp*C*C;
  const float* Wrv_p = W_rv + sp*C*C;
  float bs=0, bv0=0, bv1=0, bv2=0, rs=0, rv0=0, rv1=0, rv2=0;
  for (int c=0;c<C;++c){
    float wds = W_ds[c*C+d], wdv = W_dv[c*C+d];
    float wrs = Wrs_p[c*C+d], wrv = Wrv_p[c*C+d];
    bs  += as_l[ni][c]*wds;
    bv0 += av_l[ni][0][c]*wdv; bv1 += av_l[ni][1][c]*wdv; bv2 += av_l[ni][2][c]*wdv;
    rs  += si_l[ni][c]*wrs;
    rv0 += vi_l[ni][0][c]*wrv; rv1 += vi_l[ni][1][c]*wrv; rv2 += vi_l[ni][2][c]*wrv;
  }
  float vv = bv0*bv0 + bv1*bv1 + bv2*bv2;
  float ps  = w1s[sp*C+d]*bs + w2ss[sp*C+d]*bs*bs + w2vv[sp*C+d]*vv;
  float c1v = w1v[sp*C+d], c2sv = w2sv[sp*C+d];
  float pv0 = c1v*bv0 + c2sv*bs*bv0;
  float pv1 = c1v*bv1 + c2sv*bs*bv1;
  float pv2 = c1v*bv2 + c2sv*bs*bv2;
  __syncthreads();
  as_l[ni][d] = ps; av_l[ni][0][d]=pv0; av_l[ni][1][d]=pv1; av_l[ni][2][d]=pv2;
  __syncthreads();
  float qs=0, qv0=0, qv1=0, qv2=0;
  for (int c=0;c<C;++c){
    float wps = W_ps[c*C+d], wpv = W_pv[c*C+d];
    qs  += as_l[ni][c]*wps;
    qv0 += av_l[ni][0][c]*wpv; qv1 += av_l[ni][1][c]*wpv; qv2 += av_l[ni][2][c]*wpv;
  }
  float fsv = qs * phi_f(fabsf(qs)) + rs;
  float nv = sqrtf(qv0*qv0 + qv1*qv1 + qv2*qv2);
  float ph = phi_f(nv);
  float fv0 = qv0*ph + rv0;
  float fv1 = qv1*ph + rv1;
  float fv2 = qv2*ph + rv2;
  out[FS_OFF + n*C + d] = fsv;
  float* fvo = &out[FV_OFF + (size_t)(n*C + d)*3];
  fvo[0]=fv0; fvo[1]=fv1; fvo[2]=fv2;
  #pragma unroll
  for (int h=0; h<HEADS; ++h){
    float r = fsv * w_read[h*C + d];
    #pragma unroll
    for (int off=32; off>0; off>>=1) r += __shfl_down(r, off);
    if (d == 0) out[n*HEADS + h] = r;
  }
}

extern "C" void kernel_launch(void* const* d_in, const int* in_sizes, int n_in,
                              void* d_out, int out_size, void* d_ws, size_t ws_size,
                              hipStream_t stream)
{
  const float* ev   = (const float*)d_in[0];
  const float* nfs  = (const float*)d_in[1];
  const float* nfv  = (const float*)d_in[2];
  const float* re   = (const float*)d_in[3];
  const int*   spec = (const int*)d_in[4];
  const int*   snd  = (const int*)d_in[5];
  const int*   rcv  = (const int*)d_in[6];
  const float* W_rs = (const float*)d_in[7];
  const float* W_rv = (const float*)d_in[8];
  const float* Wus  = (const float*)d_in[9];
  const float* Wuv  = (const float*)d_in[10];
  const float* Wr1  = (const float*)d_in[11];
  const float* Wr2  = (const float*)d_in[12];
  const float* Wds  = (const float*)d_in[13];
  const float* Wdv  = (const float*)d_in[14];
  const float* w1s  = (const float*)d_in[15];
  const float* w1v  = (const float*)d_in[16];
  const float* w2ss = (const float*)d_in[17];
  const float* w2vv = (const float*)d_in[18];
  const float* w2sv = (const float*)d_in[19];
  const float* Wps  = (const float*)d_in[20];
  const float* Wpv  = (const float*)d_in[21];
  const float* wrd  = (const float*)d_in[22];

  float* out = (float*)d_out;
  float* ws  = (float*)d_ws;
  // ws layout (f32 units)
  ushort4* suv  = (ushort4*)ws;            // 2,560,000 f32-equiv (10.24 MB)
  float*   a_s  = ws + 2560000;            // 1,280,000
  float*   a_v  = ws + 3840000;            // 3,840,000
  int*    count = (int*)(ws + 7680000);    // 20,000
  int*    cursr = (int*)(ws + 7700000);    // 20,000
  int*    snd_s = (int*)(ws + 7720000);    // 320,000
  int*    rcv_s = (int*)(ws + 8040000);    // 320,000
  float4* u_s   = (float4*)(ws + 8360000); // 1,280,000 f32 (16 B/edge)
  float*  re_s  = ws + 9640000;            // 2,560,000
  unsigned short* wr2t = (unsigned short*)(ws + 12200000);  // 20,480 bf16

  hipMemsetAsync(a_s, 0, (size_t)5120000*sizeof(float), stream);   // a_s + a_v
  hipMemsetAsync(count, 0, (size_t)N_NODES*sizeof(int), stream);

  wr2t_kernel<<<(320*64)/256, 256, 0, stream>>>(Wr2, wr2t);
  node_up_kernel<<<N_NODES/4, 256, 0, stream>>>(nfs, nfv, Wus, Wuv, suv);
  hist_kernel<<<E_EDGES/256, 256, 0, stream>>>(rcv, count);
  scan_kernel<<<1, 1024, 0, stream>>>(count, cursr);
  scatter_kernel<<<E_EDGES/256, 256, 0, stream>>>(snd, rcv, ev, re, cursr,
                                                  snd_s, rcv_s, u_s, re_s);
  edge_kernel<<<NT, 512, 0, stream>>>(u_s, re_s, snd_s, rcv_s, Wr1, wr2t,
                                      suv, a_s, a_v);
  node_post_kernel<<<N_NODES/4, 256, 0, stream>>>(a_s, a_v, nfs, nfv, spec,
      W_rs, W_rv, Wds, Wdv, w1s, w1v, w2ss, w2vv, w2sv, Wps, Wpv, wrd, out);
}

// Round 6
// 411.167 us; speedup vs baseline: 1.0982x; 1.0552x over previous
//
#include <hip/hip_runtime.h>

#define N_NODES 20000
#define C 64
#define E_EDGES 320000
#define S_SPEC 64
#define R_DIM 8
#define HR 64
#define HEADS 2
#define TE 128
#define NT (E_EDGES/TE)          // 2500 blocks
#define HPAD 68                  // padded bf16 row stride (k-dim)
#define NSLOT 24                 // tile-local receiver slots in LDS
#define INV_AVG (1.0f/16.0f)

// out layout: node_out [0,40000) ; f_s [40000, 1320000) ; f_v [1320000, 5160000)
#define FS_OFF 40000
#define FV_OFF 1320000

typedef short bf16x4 __attribute__((ext_vector_type(4)));
typedef float f32x4  __attribute__((ext_vector_type(4)));

__device__ __forceinline__ unsigned short f2bf(float f){
  unsigned u = __float_as_uint(f);
  u += 0x7fffu + ((u >> 16) & 1u);
  return (unsigned short)(u >> 16);
}
__device__ __forceinline__ float bf2f(unsigned short b){
  return __uint_as_float(((unsigned)b) << 16);
}
__device__ __forceinline__ float phi_f(float x){
  float n = x * 0.5f;
  float s = (n > 0.0f) ? expf(-1.0f/n) : 0.0f;
  return 1.0f / (1.0f + n * s);
}

// ---------------- prep: Wr2T[n][k] = bf16(Wr2[k][n] / AVG)  (320x64) ------------------
__global__ __launch_bounds__(256) void wr2t_kernel(const float* __restrict__ Wr2,
                                                   unsigned short* __restrict__ wr2t){
  int idx = blockIdx.x*256 + threadIdx.x;      // n*64 + k
  int n = idx >> 6, k = idx & 63;
  wr2t[idx] = f2bf(Wr2[k*320 + n] * INV_AVG);
}

// ---------------- K1: up-projection, writes packed bf16 suv[n][c] = {s,v0,v1,v2} ------
__global__ __launch_bounds__(256) void node_up_kernel(
    const float* __restrict__ fs, const float* __restrict__ fv,
    const float* __restrict__ Wus, const float* __restrict__ Wuv,
    ushort4* __restrict__ suv){
  const int ni = threadIdx.x >> 6;
  const int d  = threadIdx.x & 63;
  const int n  = blockIdx.x*4 + ni;
  __shared__ float s_l[4][C];
  __shared__ float v_l[4][3][C];
  s_l[ni][d] = fs[n*C + d];
  #pragma unroll
  for (int x = 0; x < 3; ++x) v_l[ni][x][d] = fv[(n*C + d)*3 + x];
  __syncthreads();
  float as = 0.f, a0 = 0.f, a1 = 0.f, a2 = 0.f;
  #pragma unroll 4
  for (int c = 0; c < C; ++c){
    float wsv = Wus[c*C + d];
    float wvv = Wuv[c*C + d];
    as += s_l[ni][c] * wsv;
    a0 += v_l[ni][0][c] * wvv;
    a1 += v_l[ni][1][c] * wvv;
    a2 += v_l[ni][2][c] * wvv;
  }
  ushort4 o;
  o.x = f2bf(as); o.y = f2bf(a0); o.z = f2bf(a1); o.w = f2bf(a2);
  suv[(size_t)n*C + d] = o;
}

// ---------------- sort pass A: histogram of receivers ---------------------------------
__global__ __launch_bounds__(256) void hist_kernel(const int* __restrict__ rcv, int* __restrict__ count){
  int e = blockIdx.x*256 + threadIdx.x;
  atomicAdd(&count[rcv[e]], 1);
}

// ---------------- sort pass B: exclusive scan over 20000 counts (1 block) -------------
__global__ __launch_bounds__(1024) void scan_kernel(const int* __restrict__ count, int* __restrict__ cursor){
  __shared__ int sums[1024];
  const int t = threadIdx.x;
  const int base = t*20;
  int s = 0;
  #pragma unroll 4
  for (int i = 0; i < 20; ++i){ int idx = base+i; if (idx < N_NODES) s += count[idx]; }
  sums[t] = s;
  __syncthreads();
  for (int off = 1; off < 1024; off <<= 1){
    int v = (t >= off) ? sums[t-off] : 0;
    __syncthreads();
    sums[t] += v;
    __syncthreads();
  }
  int run = (t > 0) ? sums[t-1] : 0;
  for (int i = 0; i < 20; ++i){
    int idx = base+i;
    if (idx < N_NODES){ cursor[idx] = run; run += count[idx]; }
  }
}

// ---------------- sort pass C: scatter into sorted arrays, u pre-normalized ----------
__global__ __launch_bounds__(256) void scatter_kernel(
    const int* __restrict__ snd, const int* __restrict__ rcv,
    const float* __restrict__ ev, const float* __restrict__ re,
    int* __restrict__ cursor,
    int* __restrict__ snd_s, int* __restrict__ rcv_s,
    float4* __restrict__ u_s, float* __restrict__ re_s){
  int e = blockIdx.x*256 + threadIdx.x;
  int r = rcv[e];
  int pos = atomicAdd(&cursor[r], 1);
  snd_s[pos] = snd[e];
  rcv_s[pos] = r;
  float x = ev[e*3+0], y = ev[e*3+1], z = ev[e*3+2];
  float nr = sqrtf(x*x + y*y + z*z);
  float inv = 1.0f / fmaxf(nr, 1e-9f);
  float4 u4; u4.x = x*inv; u4.y = y*inv; u4.z = z*inv; u4.w = 0.f;
  u_s[pos] = u4;
  const float4* rp = (const float4*)&re[(size_t)e*R_DIM];
  float4 ra = rp[0], rb = rp[1];
  float4* op = (float4*)&re_s[(size_t)pos*R_DIM];
  op[0] = ra; op[1] = rb;
}

// ---------------- K2: MFMA radial GEMM + tile-local LDS accumulation scatter ----------
__global__ __launch_bounds__(512, 4) void edge_kernel(
    const float4* __restrict__ u_s, const float* __restrict__ re_s,
    const int* __restrict__ snd_s, const int* __restrict__ rcv_s,
    const float* __restrict__ Wr1, const unsigned short* __restrict__ wr2t,
    const ushort4* __restrict__ suv,
    float* __restrict__ a_s, float* __restrict__ a_v)
{
  __shared__ __align__(16) float Wr1_l[R_DIM*HR];            // 2 KB
  __shared__ __align__(16) unsigned short Wr2T_l[320*HPAD];  // 43.5 KB bf16 [n][k] padded
  __shared__ __align__(16) float re_l[TE][9];                // 4.6 KB (pad 9 kills conflicts)
  __shared__ __align__(16) float4 u_l[TE];                   // 2 KB
  __shared__ int snd_l[TE];
  __shared__ int rcv_l[TE];
  __shared__ int scan_l[TE];                                 // inclusive scan of run-flags
  __shared__ int slot_rcv[NSLOT];
  __shared__ float accum[NSLOT][4][C];                       // 24 KB tile accumulator
  __shared__ int nslots_s;

  const int t = threadIdx.x;
  const int lane = t & 63;
  const int w = t >> 6;                 // wave 0..7 = 16-edge row-block
  // bijective XCD swizzle over 2500 blocks (2500 = 8*312 + 4)
  int b = blockIdx.x;
  int xcd = b & 7, idx = b >> 3;
  const int q = NT >> 3, r = NT & 7;
  int tile = (xcd < r ? xcd*(q+1) : r*(q+1) + (xcd-r)*q) + idx;
  const int e0 = tile * TE;

  // ---- stage Wr1, Wr2T (padded), re, edge meta; zero accum ----
  Wr1_l[t] = Wr1[t];
  #pragma unroll
  for (int j = 0; j < 10; ++j){
    int i4 = t + 512*j;                 // ushort4 index, 5120 total
    ushort4 v4 = ((const ushort4*)wr2t)[i4];
    int el = i4*4; int n = el >> 6, k = el & 63;
    *(ushort4*)&Wr2T_l[n*HPAD + k] = v4;
  }
  #pragma unroll
  for (int i2 = 0; i2 < 2; ++i2){
    int idx2 = t + 512*i2;              // 1024 floats of re
    re_l[idx2 >> 3][idx2 & 7] = re_s[(size_t)e0*R_DIM + idx2];
  }
  #pragma unroll
  for (int z = t; z < NSLOT*4*C; z += 512) ((float*)accum)[z] = 0.f;
  if (t < TE){
    int e = e0 + t;
    u_l[t] = u_s[e];
    snd_l[t] = snd_s[e];
    rcv_l[t] = rcv_s[e];
  }
  __syncthreads();

  // ---- tile-local receiver slots: flag runs, Hillis-Steele scan over 128 ----
  if (t < TE) scan_l[t] = (t == 0) ? 1 : (rcv_l[t] != rcv_l[t-1] ? 1 : 0);
  __syncthreads();
  for (int off = 1; off < TE; off <<= 1){
    int v = 0;
    if (t < TE && t >= off) v = scan_l[t-off];
    __syncthreads();
    if (t < TE) scan_l[t] += v;
    __syncthreads();
  }
  if (t == 0) nslots_s = scan_l[TE-1];
  if (t < TE){
    bool flag = (t == 0) || (rcv_l[t] != rcv_l[t-1]);
    int slot = scan_l[t] - 1;
    if (flag && slot < NSLOT) slot_rcv[slot] = rcv_l[t];
  }
  __syncthreads();

  // ---- h in registers: lane computes exactly its A-fragment values ----
  // A row = w*16 + (lane&15); k = kt*16 + 4*(lane>>4) + j
  const int arow = w*16 + (lane & 15);
  const int koff = 4*(lane >> 4);
  bf16x4 ha[4];
  {
    const float* rr = re_l[arow];
    #pragma unroll
    for (int kt = 0; kt < 4; ++kt){
      short4 tmp;
      #pragma unroll
      for (int j = 0; j < 4; ++j){
        int k = kt*16 + koff + j;
        float acc = rr[0]*Wr1_l[0*HR+k] + rr[1]*Wr1_l[1*HR+k] + rr[2]*Wr1_l[2*HR+k] + rr[3]*Wr1_l[3*HR+k]
                  + rr[4]*Wr1_l[4*HR+k] + rr[5]*Wr1_l[5*HR+k] + rr[6]*Wr1_l[6*HR+k] + rr[7]*Wr1_l[7*HR+k];
        float sil = acc / (1.0f + expf(-acc));
        ((unsigned short*)&tmp)[j] = f2bf(sil);
      }
      ha[kt] = *(bf16x4*)&tmp;
    }
  }

  // ---- MFMA: W5[128][320], wave w owns rows w*16..+16, all 20 col-frags ----
  f32x4 acc[20];
  #pragma unroll
  for (int cf = 0; cf < 20; ++cf) acc[cf] = (f32x4){0.f,0.f,0.f,0.f};
  #pragma unroll
  for (int kt = 0; kt < 4; ++kt){
    bf16x4 af = ha[kt];
    #pragma unroll
    for (int cf = 0; cf < 20; ++cf){
      bf16x4 bf = *(const bf16x4*)&Wr2T_l[(cf*16 + (lane & 15))*HPAD + kt*16 + koff];
      acc[cf] = __builtin_amdgcn_mfma_f32_16x16x16bf16_1k(af, bf, acc[cf], 0, 0, 0);
    }
  }

  // ---- gather sender feats (bf16 packed), messages, flush to LDS slots ----
  {
    const int cl = lane & 15;
    const int ebase = w*16 + (lane >> 4)*4;     // this lane's 4 edges
    ushort4 gv[4][4];
    #pragma unroll
    for (int i = 0; i < 4; ++i){
      const ushort4* sp_ = &suv[(size_t)snd_l[ebase + i]*C];
      #pragma unroll
      for (int k2 = 0; k2 < 4; ++k2) gv[i][k2] = sp_[k2*16 + cl];
    }
    float ms[4], mv0[4], mv1[4], mv2[4];
    #pragma unroll
    for (int k2 = 0; k2 < 4; ++k2){ ms[k2]=0.f; mv0[k2]=0.f; mv1[k2]=0.f; mv2[k2]=0.f; }
    int cur = rcv_l[ebase];
    int cur_slot = scan_l[ebase] - 1;
    #pragma unroll
    for (int i = 0; i < 4; ++i){
      int el = ebase + i;
      int rc = rcv_l[el];
      if (rc != cur){
        if (cur_slot < NSLOT){
          #pragma unroll
          for (int k2 = 0; k2 < 4; ++k2){
            int c = k2*16 + cl;
            atomicAdd(&accum[cur_slot][0][c], ms[k2]);
            atomicAdd(&accum[cur_slot][1][c], mv0[k2]);
            atomicAdd(&accum[cur_slot][2][c], mv1[k2]);
            atomicAdd(&accum[cur_slot][3][c], mv2[k2]);
            ms[k2]=0.f; mv0[k2]=0.f; mv1[k2]=0.f; mv2[k2]=0.f;
          }
        } else {
          #pragma unroll
          for (int k2 = 0; k2 < 4; ++k2){
            int c = k2*16 + cl;
            unsafeAtomicAdd(&a_s[cur*C + c],       ms[k2]);
            unsafeAtomicAdd(&a_v[(cur*3+0)*C + c], mv0[k2]);
            unsafeAtomicAdd(&a_v[(cur*3+1)*C + c], mv1[k2]);
            unsafeAtomicAdd(&a_v[(cur*3+2)*C + c], mv2[k2]);
            ms[k2]=0.f; mv0[k2]=0.f; mv1[k2]=0.f; mv2[k2]=0.f;
          }
        }
        cur = rc; cur_slot = scan_l[el] - 1;
      }
      float u0 = u_l[el].x, u1 = u_l[el].y, u2 = u_l[el].z;
      #pragma unroll
      for (int k2 = 0; k2 < 4; ++k2){
        float se  = bf2f(gv[i][k2].x);
        float ve0 = bf2f(gv[i][k2].y);
        float ve1 = bf2f(gv[i][k2].z);
        float ve2 = bf2f(gv[i][k2].w);
        float w0 = acc[0*4+k2][i];
        float w1 = acc[1*4+k2][i];
        float w2 = acc[2*4+k2][i];
        float w3 = acc[3*4+k2][i];
        float w4 = acc[4*4+k2][i];
        float dt  = ve0*u0 + ve1*u1 + ve2*u2;
        float cr0 = ve1*u2 - ve2*u1;
        float cr1 = ve2*u0 - ve0*u2;
        float cr2 = ve0*u1 - ve1*u0;
        ms[k2]  += w0*se + w3*dt;
        mv0[k2] += w1*ve0 + w2*u0 + w4*cr0;
        mv1[k2] += w1*ve1 + w2*u1 + w4*cr1;
        mv2[k2] += w1*ve2 + w2*u2 + w4*cr2;
      }
    }
    if (cur_slot < NSLOT){
      #pragma unroll
      for (int k2 = 0; k2 < 4; ++k2){
        int c = k2*16 + cl;
        atomicAdd(&accum[cur_slot][0][c], ms[k2]);
        atomicAdd(&accum[cur_slot][1][c], mv0[k2]);
        atomicAdd(&accum[cur_slot][2][c], mv1[k2]);
        atomicAdd(&accum[cur_slot][3][c], mv2[k2]);
      }
    } else {
      #pragma unroll
      for (int k2 = 0; k2 < 4; ++k2){
        int c = k2*16 + cl;
        unsafeAtomicAdd(&a_s[cur*C + c],       ms[k2]);
        unsafeAtomicAdd(&a_v[(cur*3+0)*C + c], mv0[k2]);
        unsafeAtomicAdd(&a_v[(cur*3+1)*C + c], mv1[k2]);
        unsafeAtomicAdd(&a_v[(cur*3+2)*C + c], mv2[k2]);
      }
    }
  }
  __syncthreads();

  // ---- one coalesced atomic per (slot, field, channel) ----
  {
    int ns = nslots_s; if (ns > NSLOT) ns = NSLOT;
    for (int v = t; v < ns*256; v += 512){
      int slot = v >> 8, f = (v >> 6) & 3, c = v & 63;
      int rr = slot_rcv[slot];
      float val = accum[slot][f][c];
      if (f == 0) unsafeAtomicAdd(&a_s[rr*C + c], val);
      else        unsafeAtomicAdd(&a_v[(rr*3 + (f-1))*C + c], val);
    }
  }
}

// ---------------- K3: down-matvec, product basis, soft-norm, residual, readout (4/blk)
__global__ __launch_bounds__(256) void node_post_kernel(
    const float* __restrict__ a_s, const float* __restrict__ a_v,
    const float* __restrict__ fs_in, const float* __restrict__ fv_in,
    const int* __restrict__ species,
    const float* __restrict__ W_rs, const float* __restrict__ W_rv,
    const float* __restrict__ W_ds, const float* __restrict__ W_dv,
    const float* __restrict__ w1s, const float* __restrict__ w1v,
    const float* __restrict__ w2ss, const float* __restrict__ w2vv, const float* __restrict__ w2sv,
    const float* __restrict__ W_ps, const float* __restrict__ W_pv,
    const float* __restrict__ w_read, float* __restrict__ out)
{
  const int ni = threadIdx.x >> 6;
  const int d  = threadIdx.x & 63;
  const int n  = blockIdx.x*4 + ni;
  const int sp = species[n];
  __shared__ float as_l[4][C];
  __shared__ float av_l[4][3][C];
  __shared__ float si_l[4][C];
  __shared__ float vi_l[4][3][C];
  as_l[ni][d] = a_s[n*C + d];
  #pragma unroll
  for (int x=0;x<3;x++) av_l[ni][x][d] = a_v[(n*3+x)*C + d];
  si_l[ni][d] = fs_in[n*C + d];
  #pragma unroll
  for (int x=0;x<3;x++) vi_l[ni][x][d] = fv_in[(n*C + d)*3 + x];
  __syncthreads();
  const float* Wrs_p = W_rs + sp*C*C;
  const float* Wrv_p = W_rv + sp*C*C;
  float bs=0, bv0=0, bv1=0, bv2=0, rs=0, rv0=0, rv1=0, rv2=0;
  for (int c=0;c<C;++c){
    float wds = W_ds[c*C+d], wdv = W_dv[c*C+d];
    float wrs = Wrs_p[c*C+d], wrv = Wrv_p[c*C+d];
    bs  += as_l[ni][c]*wds;
    bv0 += av_l[ni][0][c]*wdv; bv1 += av_l[ni][1][c]*wdv; bv2 += av_l[ni][2][c]*wdv;
    rs  += si_l[ni][c]*wrs;
    rv0 += vi_l[ni][0][c]*wrv; rv1 += vi_l[ni][1][c]*wrv; rv2 += vi_l[ni][2][c]*wrv;
  }
  float vv = bv0*bv0 + bv1*bv1 + bv2*bv2;
  float ps  = w1s[sp*C+d]*bs + w2ss[sp*C+d]*bs*bs + w2vv[sp*C+d]*vv;
  float c1v = w1v[sp*C+d], c2sv = w2sv[sp*C+d];
  float pv0 = c1v*bv0 + c2sv*bs*bv0;
  float pv1 = c1v*bv1 + c2sv*bs*bv1;
  float pv2 = c1v*bv2 + c2sv*bs*bv2;
  __syncthreads();
  as_l[ni][d] = ps; av_l[ni][0][d]=pv0; av_l[ni][1][d]=pv1; av_l[ni][2][d]=pv2;
  __syncthreads();
  float qs=0, qv0=0, qv1=0, qv2=0;
  for (int c=0;c<C;++c){
    float wps = W_ps[c*C+d], wpv = W_pv[c*C+d];
    qs  += as_l[ni][c]*wps;
    qv0 += av_l[ni][0][c]*wpv; qv1 += av_l[ni][1][c]*wpv; qv2 += av_l[ni][2][c]*wpv;
  }
  float fsv = qs * phi_f(fabsf(qs)) + rs;
  float nv = sqrtf(qv0*qv0 + qv1*qv1 + qv2*qv2);
  float ph = phi_f(nv);
  float fv0 = qv0*ph + rv0;
  float fv1 = qv1*ph + rv1;
  float fv2 = qv2*ph + rv2;
  out[FS_OFF + n*C + d] = fsv;
  float* fvo = &out[FV_OFF + (size_t)(n*C + d)*3];
  fvo[0]=fv0; fvo[1]=fv1; fvo[2]=fv2;
  #pragma unroll
  for (int h=0; h<HEADS; ++h){
    float r = fsv * w_read[h*C + d];
    #pragma unroll
    for (int off=32; off>0; off>>=1) r += __shfl_down(r, off);
    if (d == 0) out[n*HEADS + h] = r;
  }
}

extern "C" void kernel_launch(void* const* d_in, const int* in_sizes, int n_in,
                              void* d_out, int out_size, void* d_ws, size_t ws_size,
                              hipStream_t stream)
{
  const float* ev   = (const float*)d_in[0];
  const float* nfs  = (const float*)d_in[1];
  const float* nfv  = (const float*)d_in[2];
  const float* re   = (const float*)d_in[3];
  const int*   spec = (const int*)d_in[4];
  const int*   snd  = (const int*)d_in[5];
  const int*   rcv  = (const int*)d_in[6];
  const float* W_rs = (const float*)d_in[7];
  const float* W_rv = (const float*)d_in[8];
  const float* Wus  = (const float*)d_in[9];
  const float* Wuv  = (const float*)d_in[10];
  const float* Wr1  = (const float*)d_in[11];
  const float* Wr2  = (const float*)d_in[12];
  const float* Wds  = (const float*)d_in[13];
  const float* Wdv  = (const float*)d_in[14];
  const float* w1s  = (const float*)d_in[15];
  const float* w1v  = (const float*)d_in[16];
  const float* w2ss = (const float*)d_in[17];
  const float* w2vv = (const float*)d_in[18];
  const float* w2sv = (const float*)d_in[19];
  const float* Wps  = (const float*)d_in[20];
  const float* Wpv  = (const float*)d_in[21];
  const float* wrd  = (const float*)d_in[22];

  float* out = (float*)d_out;
  float* ws  = (float*)d_ws;
  // ws layout (f32 units)
  ushort4* suv  = (ushort4*)ws;            // 2,560,000 f32-equiv (10.24 MB)
  float*   a_s  = ws + 2560000;            // 1,280,000
  float*   a_v  = ws + 3840000;            // 3,840,000
  int*    count = (int*)(ws + 7680000);    // 20,000
  int*    cursr = (int*)(ws + 7700000);    // 20,000
  int*    snd_s = (int*)(ws + 7720000);    // 320,000
  int*    rcv_s = (int*)(ws + 8040000);    // 320,000
  float4* u_s   = (float4*)(ws + 8360000); // 1,280,000 f32 (16 B/edge)
  float*  re_s  = ws + 9640000;            // 2,560,000
  unsigned short* wr2t = (unsigned short*)(ws + 12200000);  // 20,480 bf16

  hipMemsetAsync(a_s, 0, (size_t)5120000*sizeof(float), stream);   // a_s + a_v
  hipMemsetAsync(count, 0, (size_t)N_NODES*sizeof(int), stream);

  wr2t_kernel<<<(320*64)/256, 256, 0, stream>>>(Wr2, wr2t);
  node_up_kernel<<<N_NODES/4, 256, 0, stream>>>(nfs, nfv, Wus, Wuv, suv);
  hist_kernel<<<E_EDGES/256, 256, 0, stream>>>(rcv, count);
  scan_kernel<<<1, 1024, 0, stream>>>(count, cursr);
  scatter_kernel<<<E_EDGES/256, 256, 0, stream>>>(snd, rcv, ev, re, cursr,
                                                  snd_s, rcv_s, u_s, re_s);
  edge_kernel<<<NT, 512, 0, stream>>>(u_s, re_s, snd_s, rcv_s, Wr1, wr2t,
                                      suv, a_s, a_v);
  node_post_kernel<<<N_NODES/4, 256, 0, stream>>>(a_s, a_v, nfs, nfv, spec,
      W_rs, W_rv, Wds, Wdv, w1s, w1v, w2ss, w2vv, w2sv, Wps, Wpv, wrd, out);
}